// Round 6
// baseline (59.368 us; speedup 1.0000x reference)
//
#include <hip/hip_runtime.h>

#define B_ 2
#define N_ 16384
#define M_ 8192

typedef float f32x4 __attribute__((ext_vector_type(4)));
typedef short s16x8 __attribute__((ext_vector_type(8)));

__device__ inline float min3f(float a, float b, float c) {
    float d;
    asm("v_min3_f32 %0, %1, %2, %3" : "=v"(d) : "v"(a), "v"(b), "v"(c));
    return d;
}

// RNE f32 -> bf16 (bits)
__device__ inline unsigned short f2bf(float f) {
    unsigned int u = __float_as_uint(f);
    u += 0x7FFFu + ((u >> 16) & 1u);
    return (unsigned short)(u >> 16);
}
__device__ inline float bf2f(unsigned short h) {
    return __uint_as_float(((unsigned int)h) << 16);
}
// 3-way bf16 split: v ~= h + m + l to ~2^-24 rel
__device__ inline void split3(float v, unsigned short& hb, unsigned short& mb,
                              unsigned short& lb) {
    hb = f2bf(v);
    float r1 = v - bf2f(hb);
    mb = f2bf(r1);
    float r2 = r1 - bf2f(mb);
    lb = f2bf(r2);
}

// ---------------- reductions ----------------

__device__ inline float blk_reduce_max(float v, float* red) {
    #pragma unroll
    for (int off = 32; off; off >>= 1) v = fmaxf(v, __shfl_xor(v, off));
    int wid = threadIdx.x >> 6;
    int lane = threadIdx.x & 63;
    int nw = blockDim.x >> 6;
    if (lane == 0) red[wid] = v;
    __syncthreads();
    if (wid == 0) {
        v = (lane < nw) ? red[lane] : -3.402823466e38f;
        #pragma unroll
        for (int off = 32; off; off >>= 1) v = fmaxf(v, __shfl_xor(v, off));
        if (lane == 0) red[0] = v;
    }
    __syncthreads();
    v = red[0];
    __syncthreads();
    return v;
}

__device__ inline float blk_reduce_sum(float v, float* red) {
    #pragma unroll
    for (int off = 32; off; off >>= 1) v += __shfl_xor(v, off);
    int wid = threadIdx.x >> 6;
    int lane = threadIdx.x & 63;
    int nw = blockDim.x >> 6;
    if (lane == 0) red[wid] = v;
    __syncthreads();
    if (wid == 0) {
        v = (lane < nw) ? red[lane] : 0.0f;
        #pragma unroll
        for (int off = 32; off; off >>= 1) v += __shfl_xor(v, off);
        if (lane == 0) red[0] = v;
    }
    __syncthreads();
    v = red[0];
    __syncthreads();
    return v;
}

// ---------------- kernels ----------------

__global__ __launch_bounds__(256) void init_ws(const float* __restrict__ wts,
                                               unsigned int* min1, unsigned int* min2,
                                               float* __restrict__ wmax_part,
                                               float* out) {
    int i = blockIdx.x * 256 + threadIdx.x;
    if (i < B_ * N_) min1[i] = 0x7F7FFFFFu;  // FLT_MAX bits
    if (i < B_ * M_) min2[i] = 0x7F7FFFFFu;
    if (i == 0) out[0] = 0.0f;

    float v = wts[i];
    #pragma unroll
    for (int off = 32; off; off >>= 1) v = fmaxf(v, __shfl_xor(v, off));
    if ((threadIdx.x & 63) == 0)
        wmax_part[blockIdx.x * 4 + (threadIdx.x >> 6)] = v;  // 4 waves/block
}

// Single-pass MFMA chamfer sweep — ROUND-4 PROVEN BASE (absmax 0.0), with one
// change: LDS squeeze 36KB -> 24KB for occupancy (4 -> 6 blocks/CU).
//   K slots 0-17: 6 product groups of 3-way bf16 splits of u=-2x and y
//   K slots 18-23: sq1 split x 1 ; 1 x sq2 split ; slots 24-31 zero.
// Group 3 (k-slots 24-31) of BOTH operands is all-zero, so Ash/Bsh store only
// groups 0-2 ([16][48], 12KB each); lanes 48-63 substitute a zero fragment via
// a guarded read -> MFMA inputs bit-identical to round 4. m2sh is deleted:
// after the two shfl_xor, lanes l<16 hold the wave's col-min and atomicMin it
// directly (4.2M atomics total; rounds 0-3 sustained 4M with no counter
// footprint). LDS = 24576B -> 6 blocks/CU = 24 waves/CU (was 16 at 36864B).
// NO launch_bounds waves pin (round-5 lesson: the (256,8) pin + in-lane build
// combo produced inf; keep compiler's natural ~64 VGPR allocation).
__global__ __launch_bounds__(256) void chamfer_mfma(
        const float* __restrict__ p1, const float* __restrict__ p2,
        unsigned int* __restrict__ min1, unsigned int* __restrict__ min2) {
    __shared__ s16x8 Ash[16][48];        // 16 owner tiles x groups 0-2 = 12KB
    __shared__ s16x8 Bsh[16][48];        // 16 scan  tiles x groups 0-2 = 12KB

    const int bid = blockIdx.x;
    const int b   = bid >> 11;           // 2048 blocks per batch
    const int rr  = bid & 2047;
    const int ob  = rr >> 5;             // 64 owner blocks
    const int bin = rr & 31;             // 32 scan bins
    const int nb  = ob * 256;
    const int mb  = bin * 256;

    const int t = threadIdx.x;
    const short ONE = (short)0x3F80;     // bf16(1.0)

    // ---- stage A: owner rows (u = -2x, sq1 = x.x) ----
    {
        const float* px = p1 + ((size_t)b * N_ + nb + t) * 3;
        float x0 = px[0], x1 = px[1], x2 = px[2];
        float sq = fmaf(x0, x0, fmaf(x1, x1, x2 * x2));
        unsigned short uh[3], um[3], ul[3], s1[3];
        split3(-2.f * x0, uh[0], um[0], ul[0]);
        split3(-2.f * x1, uh[1], um[1], ul[1]);
        split3(-2.f * x2, uh[2], um[2], ul[2]);
        split3(sq, s1[0], s1[1], s1[2]);
        s16x8 g0 = {(short)uh[0], (short)uh[1], (short)uh[2], (short)uh[0],
                    (short)uh[1], (short)uh[2], (short)um[0], (short)um[1]};
        s16x8 g1 = {(short)um[2], (short)uh[0], (short)uh[1], (short)uh[2],
                    (short)ul[0], (short)ul[1], (short)ul[2], (short)um[0]};
        s16x8 g2 = {(short)um[1], (short)um[2], (short)s1[0], (short)s1[1],
                    (short)s1[2], ONE, ONE, ONE};
        int tl = t >> 4, c = t & 15;
        Ash[tl][ 0 + c] = g0;
        Ash[tl][16 + c] = g1;
        Ash[tl][32 + c] = g2;
    }
    // ---- stage B: scanned cols (y, sq2 = y.y) ----
    {
        const float* py = p2 + ((size_t)b * M_ + mb + t) * 3;
        float y0 = py[0], y1 = py[1], y2 = py[2];
        float sq = fmaf(y0, y0, fmaf(y1, y1, y2 * y2));
        unsigned short yh[3], ym[3], yl[3], s2[3];
        split3(y0, yh[0], ym[0], yl[0]);
        split3(y1, yh[1], ym[1], yl[1]);
        split3(y2, yh[2], ym[2], yl[2]);
        split3(sq, s2[0], s2[1], s2[2]);
        s16x8 g0 = {(short)yh[0], (short)yh[1], (short)yh[2], (short)ym[0],
                    (short)ym[1], (short)ym[2], (short)yh[0], (short)yh[1]};
        s16x8 g1 = {(short)yh[2], (short)yl[0], (short)yl[1], (short)yl[2],
                    (short)yh[0], (short)yh[1], (short)yh[2], (short)ym[0]};
        s16x8 g2 = {(short)ym[1], (short)ym[2], ONE, ONE, ONE,
                    (short)s2[0], (short)s2[1], (short)s2[2]};
        int tl = t >> 4, c = t & 15;
        Bsh[tl][ 0 + c] = g0;
        Bsh[tl][16 + c] = g1;
        Bsh[tl][32 + c] = g2;
    }
    __syncthreads();

    const int w = t >> 6, l = t & 63;
    const s16x8 zfrag = {0, 0, 0, 0, 0, 0, 0, 0};

    s16x8 Af[4];
    #pragma unroll
    for (int r = 0; r < 4; r++)
        Af[r] = (l < 48) ? Ash[4 * w + r][l] : zfrag;   // group 3 == zeros

    f32x4 mn1v[4];
    #pragma unroll
    for (int r = 0; r < 4; r++)
        mn1v[r] = (f32x4){3.402823466e38f, 3.402823466e38f,
                          3.402823466e38f, 3.402823466e38f};

    const f32x4 zacc = {0.f, 0.f, 0.f, 0.f};
    unsigned int* m2g = min2 + (size_t)b * M_;

    #pragma unroll 4
    for (int mt = 0; mt < 16; mt++) {
        s16x8 Bf = (l < 48) ? Bsh[mt][l] : zfrag;       // group 3 == zeros
        float m2v = 3.402823466e38f;
        #pragma unroll
        for (int r = 0; r < 4; r++) {
            f32x4 acc = __builtin_amdgcn_mfma_f32_16x16x32_bf16(Af[r], Bf, zacc, 0, 0, 0);
            mn1v[r].x = fminf(mn1v[r].x, acc.x);
            mn1v[r].y = fminf(mn1v[r].y, acc.y);
            mn1v[r].z = fminf(mn1v[r].z, acc.z);
            mn1v[r].w = fminf(mn1v[r].w, acc.w);
            m2v = min3f(m2v, acc.x, acc.y);
            m2v = min3f(m2v, acc.z, acc.w);
        }
        // col-min across the 4 row-groups (lanes ^16, ^32); col = l&15
        m2v = fminf(m2v, __shfl_xor(m2v, 16));
        m2v = fminf(m2v, __shfl_xor(m2v, 32));
        if (l < 16)
            atomicMin(&m2g[mb + mt * 16 + l], __float_as_uint(m2v));
    }

    // ---- epilogue: min1 (reduce over the 16 cols held across lanes l&15) ----
    unsigned int* m1g = min1 + (size_t)b * N_;
    #pragma unroll
    for (int r = 0; r < 4; r++) {
        #pragma unroll
        for (int q = 0; q < 4; q++) {
            float v = mn1v[r][q];
            v = fminf(v, __shfl_xor(v, 1));
            v = fminf(v, __shfl_xor(v, 2));
            v = fminf(v, __shfl_xor(v, 4));
            v = fminf(v, __shfl_xor(v, 8));
            if ((l & 15) == 0) {
                int row = nb + (4 * w + r) * 16 + (l >> 4) * 4 + q;
                // distances non-negative: float bits order as uint
                atomicMin(&m1g[row], __float_as_uint(v));
            }
        }
    }
}

__global__ __launch_bounds__(1024) void finalize_kernel(
        const float* __restrict__ wts,
        const float* __restrict__ min1,
        const float* __restrict__ min2,
        const float* __restrict__ wmax_part,
        float* __restrict__ out) {
    __shared__ float red[16];
    int b = blockIdx.x;
    const float* wb = wts + b * N_;
    const float* m1 = min1 + b * N_;
    const float* m2 = min2 + b * M_;

    float lmax = (threadIdx.x < 256) ? wmax_part[b * 256 + threadIdx.x]
                                     : -3.402823466e38f;
    float gmax = blk_reduce_max(lmax, red);

    float se = 0.0f, swm = 0.0f;
    for (int i = threadIdx.x; i < N_ / 4; i += blockDim.x) {
        f32x4 w4 = ((const f32x4*)wb)[i];
        f32x4 m4 = ((const f32x4*)m1)[i];
        #pragma unroll
        for (int k = 0; k < 4; k++) {
            float e = expf(w4[k] - gmax);
            se += e;
            swm += e * m4[k];
        }
    }
    float tse = blk_reduce_sum(se, red);
    float tswm = blk_reduce_sum(swm, red);

    float sm2 = 0.0f;
    for (int i = threadIdx.x; i < M_ / 4; i += blockDim.x) {
        f32x4 m4 = ((const f32x4*)m2)[i];
        sm2 += (m4.x + m4.y) + (m4.z + m4.w);
    }
    float tsm2 = blk_reduce_sum(sm2, red);

    if (threadIdx.x == 0)
        atomicAdd(out, (tswm / tse + tsm2 * (1.0f / (float)M_)) * (1.0f / (float)B_));
}

// ---------------- launch ----------------

extern "C" void kernel_launch(void* const* d_in, const int* in_sizes, int n_in,
                              void* d_out, int out_size, void* d_ws, size_t ws_size,
                              hipStream_t stream) {
    const float* p1  = (const float*)d_in[0];  // (B, N, 3)
    const float* p2  = (const float*)d_in[1];  // (B, M, 3)
    const float* wts = (const float*)d_in[2];  // (B, N)
    float* out = (float*)d_out;

    unsigned int* min1 = (unsigned int*)d_ws;        // B*N
    unsigned int* min2 = min1 + B_ * N_;             // B*M
    float* wmax_part = (float*)(min2 + B_ * M_);     // 128 blocks * 4 waves = 512

    init_ws<<<dim3((B_ * N_) / 256), dim3(256), 0, stream>>>(wts, min1, min2,
                                                             wmax_part, out);
    chamfer_mfma<<<dim3(4096), dim3(256), 0, stream>>>(p1, p2, min1, min2);
    finalize_kernel<<<dim3(B_), dim3(1024), 0, stream>>>(
        wts, (const float*)min1, (const float*)min2, wmax_part, out);
}